// Round 19
// baseline (189.485 us; speedup 1.0000x reference)
//
#include <hip/hip_runtime.h>
#include <hip/hip_bf16.h>

#define B_ 4
#define T_ 2048
#define C_ 1024
#define H_ 16
#define D_ 64

typedef __bf16 bf16x8 __attribute__((ext_vector_type(8)));
typedef float f32x4 __attribute__((ext_vector_type(4)));
typedef float f32x16 __attribute__((ext_vector_type(16)));

__device__ __forceinline__ unsigned short f2bs(float f) {
    __hip_bfloat16 h = __float2bfloat16(f);
    return *reinterpret_cast<unsigned short*>(&h);
}

// raw v_exp_f32 (2^x): one trans op vs OCML exp2f's guarded sequence.
__device__ __forceinline__ float fexp2(float x) {
    float r;
    asm("v_exp_f32 %0, %1" : "=v"(r) : "v"(x));
    return r;
}

// pack two f32 -> one u32 of 2 bf16 (low = a, high = b)
__device__ __forceinline__ unsigned cvtpk(float a, float b) {
    unsigned r;
    asm("v_cvt_pk_bf16_f32 %0, %1, %2" : "=v"(r) : "v"(a), "v"(b));
    return r;
}

// exchange a.hi-lanes <-> b.lo-lanes (T12)
__device__ __forceinline__ void plane32swap(unsigned& a, unsigned& b, int hi) {
#if __has_builtin(__builtin_amdgcn_permlane32_swap)
    typedef int i32x2 __attribute__((ext_vector_type(2)));
    i32x2 r = __builtin_amdgcn_permlane32_swap((int)a, (int)b, false, false);
    a = (unsigned)r.x; b = (unsigned)r.y;
#else
    unsigned v = hi ? a : b;
    unsigned e = __shfl_xor(v, 32);
    unsigned na = hi ? e : a;
    unsigned nb = hi ? b : e;
    a = na; b = nb;
#endif
}

// XOR swizzle for [rows][64] bf16 LDS tiles: permutes 8-elem (16B) chunks
// within a row by row&7 -> spreads column-slice reads across 8 bank-groups.
__device__ __forceinline__ int swz(int row, int col) {
    return (row * 64 + col) ^ ((row & 7) << 3);
}

// async global->LDS 16B: linear LDS dest (wave-uniform base + lane*16).
__device__ __forceinline__ void gload16(const void* g, void* l) {
    auto gp = (const __attribute__((address_space(1))) void*)(g);
    auto lp = (__attribute__((address_space(3))) void*)(uintptr_t)(l);
    __builtin_amdgcn_global_load_lds(gp, lp, 16, 0, 0);
}

// ---- fused preprocessing: x->bf16 convert + both weight transposes ----
__global__ __launch_bounds__(256)
void prep_fused(const float* __restrict__ x, unsigned short* __restrict__ xb,
                const float* __restrict__ in1, unsigned short* __restrict__ out1,
                const float* __restrict__ in2, unsigned short* __restrict__ out2) {
    __shared__ float tile[64][65];
    const int bid = blockIdx.x;
    if (bid < 8192) {
        int i = bid * 256 + threadIdx.x;
        float4 v = ((const float4*)x)[i];
        union { unsigned short h[4]; uint2 u; } pk;
        pk.h[0] = f2bs(v.x); pk.h[1] = f2bs(v.y);
        pk.h[2] = f2bs(v.z); pk.h[3] = f2bs(v.w);
        ((uint2*)xb)[i] = pk.u;
        return;
    }
    const int tb = bid - 8192;
    const int bx = tb & 63;
    const int by = tb >> 6;
    const int tx = threadIdx.x & 63;
    const int ty = threadIdx.x >> 6;
    const bool second = bx >= 48;
    const float* in = second ? in2 : in1;
    unsigned short* out = second ? out2 : out1;
    const int C = second ? 1024 : 3072;
    const int R = 1024;
    const int c0 = (second ? (bx - 48) : bx) * 64;
    const int r0 = by * 64;
    #pragma unroll
    for (int i = 0; i < 16; ++i) {
        int r = ty * 16 + i;
        tile[r][tx] = in[(size_t)(r0 + r) * C + c0 + tx];
    }
    __syncthreads();
    #pragma unroll
    for (int i = 0; i < 16; ++i) {
        int r = ty * 16 + i;
        out[(size_t)(c0 + r) * R + r0 + tx] = f2bs(tile[tx][r]);
    }
}

// ======== 128^2 GEMM, TRIPLE-buffered, counted vmcnt (T4-minimal) ========
// Identical 2-phase body/wave-layout to the proven kernel; the ONLY change:
// 3 LDS buffers + prefetch distance 2, so the per-step barrier waits
// vmcnt(8) -- draining the 2-steps-old stage while last step's 8 loads
// stay in flight (each load gets ~2 K-steps of latency cover instead of 1).
// Per-wave FIFO exact: every wave issues exactly 8 gload16 per stage.
// Hazard: step i stages buf[(i+2)%3]; its prior readers (step i-1) consumed
// their ds_reads before passing barrier i (reads feed MFMAs issued before
// the barrier in program order; sched_barrier(0x7) pins VMEM/DS/MFMA so the
// compiler cannot sink them past it). vmcnt(0) only on the last step.
// LDS 96 KB -> 1 block/CU; bet: drain elimination > lost inter-block hiding.
template<int MODE, int K>
__global__ __launch_bounds__(256)
void gemm_bt3(const unsigned short* __restrict__ A,
              const unsigned short* __restrict__ Bt,
              float* __restrict__ Out, int N_out,
              unsigned short* __restrict__ Qb,
              unsigned short* __restrict__ Kb,
              unsigned short* __restrict__ Vt) {
    __shared__ alignas(16) unsigned short As[3][128 * 64];
    __shared__ alignas(16) unsigned short Bs[3][128 * 64];
    const int tid = threadIdx.x;
    const int l = tid & 63;
    const int c16 = l & 15, lq = l >> 4;
    const int wv = tid >> 6;
    const int wrow = wv >> 1, wcol = wv & 1;
    const int m0 = blockIdx.x * 128, n0 = blockIdx.y * 128;

    f32x4 acc[4][4];
    #pragma unroll
    for (int i = 0; i < 4; ++i)
        #pragma unroll
        for (int j = 0; j < 4; ++j)
            acc[i][j] = f32x4{0.f, 0.f, 0.f, 0.f};

    const int srow = tid >> 3;            // 0..31
    const int scs  = tid & 7;             // 16B chunk within row
    const int ldsbase = (tid & ~63) * 8;  // wave-uniform element base (p=0)

    // stage one K-tile into buffer b: exactly 8 gload16 per thread (FIFO unit)
    auto stage = [&](int k0, int b) {
        #pragma unroll
        for (int p = 0; p < 4; ++p) {
            int row = p * 32 + srow;
            int csw = 8 * (scs ^ (row & 7));   // inverse-swizzled source chunk
            gload16(&A[(size_t)(m0 + row) * K + k0 + csw], &As[b][p * 2048 + ldsbase]);
            gload16(&Bt[(size_t)(n0 + row) * K + k0 + csw], &Bs[b][p * 2048 + ldsbase]);
        }
    };

    stage(0, 0);
    if (K > 64) stage(64, 1);
    constexpr int NK = K >> 6;
    int cur = 0;                          // buffer holding tile i
    for (int i = 0; i < NK; ++i) {
        __builtin_amdgcn_sched_barrier(0x7);
        if (i == NK - 1) asm volatile("s_waitcnt vmcnt(0)" ::: "memory");
        else             asm volatile("s_waitcnt vmcnt(8)" ::: "memory");
        __builtin_amdgcn_s_barrier();
        __builtin_amdgcn_sched_barrier(0x7);
        if (i + 2 < NK) {
            int nb = cur + 2; if (nb >= 3) nb -= 3;
            stage((i + 2) << 6, nb);
        }
        const unsigned short* Al = As[cur];
        const unsigned short* Bl = Bs[cur];
        #pragma unroll
        for (int kk = 0; kk < 64; kk += 32) {
            bf16x8 af[4], bfv[4];
            int koff = kk + lq * 8;
            #pragma unroll
            for (int t = 0; t < 4; ++t) {
                af[t]  = *(const bf16x8*)&Al[swz(wrow * 64 + t * 16 + c16, koff)];
                bfv[t] = *(const bf16x8*)&Bl[swz(wcol * 64 + t * 16 + c16, koff)];
            }
            #pragma unroll
            for (int mi = 0; mi < 4; ++mi)
                #pragma unroll
                for (int ni = 0; ni < 4; ++ni)
                    acc[mi][ni] = __builtin_amdgcn_mfma_f32_16x16x32_bf16(
                        af[mi], bfv[ni], acc[mi][ni], 0, 0, 0);
        }
        ++cur; if (cur >= 3) cur -= 3;
    }

    #pragma unroll
    for (int mi = 0; mi < 4; ++mi) {
        #pragma unroll
        for (int ni = 0; ni < 4; ++ni) {
            #pragma unroll
            for (int r = 0; r < 4; ++r) {
                float v = acc[mi][ni][r];
                int row = m0 + wrow * 64 + mi * 16 + lq * 4 + r;
                int col = n0 + wcol * 64 + ni * 16 + c16;
                if (MODE == 1) {
                    Out[(size_t)row * N_out + col] = v;
                } else {
                    int which = col >> 10;
                    int c = col & 1023;
                    int h = c >> 6, d = c & 63;
                    int b = row >> 11, t = row & 2047;
                    int bh = b * H_ + h;
                    if (which == 0)  // fold 1/sqrt(64) * log2(e) so attn uses exp2
                        Qb[((size_t)(bh * T_ + t)) * D_ + d] = f2bs(v * 0.1803368801111204f);
                    else if (which == 1)
                        Kb[((size_t)(bh * T_ + t)) * D_ + d] = f2bs(v);
                    else
                        Vt[((size_t)(bh * D_ + d)) * T_ + t] = f2bs(v);
                }
            }
        }
    }
}

// ---------------- BK=64 128^2 dbuf GEMM (proven; final projection) ----------
template<int MODE>
__global__ __launch_bounds__(256)
void gemm_bt(const unsigned short* __restrict__ A,
             const unsigned short* __restrict__ Bt,
             float* __restrict__ Out, int N_out,
             unsigned short* __restrict__ Qb,
             unsigned short* __restrict__ Kb,
             unsigned short* __restrict__ Vt,
             int K) {
    __shared__ alignas(16) unsigned short As[2][128 * 64];
    __shared__ alignas(16) unsigned short Bs[2][128 * 64];
    const int tid = threadIdx.x;
    const int l = tid & 63;
    const int c16 = l & 15, lq = l >> 4;
    const int wv = tid >> 6;
    const int wrow = wv >> 1, wcol = wv & 1;
    const int m0 = blockIdx.x * 128, n0 = blockIdx.y * 128;

    f32x4 acc[4][4];
    #pragma unroll
    for (int i = 0; i < 4; ++i)
        #pragma unroll
        for (int j = 0; j < 4; ++j)
            acc[i][j] = f32x4{0.f, 0.f, 0.f, 0.f};

    const int srow = tid >> 3;
    const int scs  = tid & 7;
    const int ldsbase = (tid & ~63) * 8;

    auto stage = [&](int k0, int buf) {
        #pragma unroll
        for (int p = 0; p < 4; ++p) {
            int row = p * 32 + srow;
            int csw = 8 * (scs ^ (row & 7));
            gload16(&A[(size_t)(m0 + row) * K + k0 + csw], &As[buf][p * 2048 + ldsbase]);
            gload16(&Bt[(size_t)(n0 + row) * K + k0 + csw], &Bs[buf][p * 2048 + ldsbase]);
        }
    };

    stage(0, 0);
    const int NK = K >> 6;
    for (int i = 0; i < NK; ++i) {
        __syncthreads();
        if (i + 1 < NK) stage((i + 1) << 6, (i + 1) & 1);
        const unsigned short* Al = As[i & 1];
        const unsigned short* Bl = Bs[i & 1];
        #pragma unroll
        for (int kk = 0; kk < 64; kk += 32) {
            bf16x8 af[4], bfv[4];
            int koff = kk + lq * 8;
            #pragma unroll
            for (int t = 0; t < 4; ++t) {
                af[t]  = *(const bf16x8*)&Al[swz(wrow * 64 + t * 16 + c16, koff)];
                bfv[t] = *(const bf16x8*)&Bl[swz(wcol * 64 + t * 16 + c16, koff)];
            }
            #pragma unroll
            for (int mi = 0; mi < 4; ++mi)
                #pragma unroll
                for (int ni = 0; ni < 4; ++ni)
                    acc[mi][ni] = __builtin_amdgcn_mfma_f32_16x16x32_bf16(
                        af[mi], bfv[ni], acc[mi][ni], 0, 0, 0);
        }
    }

    #pragma unroll
    for (int mi = 0; mi < 4; ++mi) {
        #pragma unroll
        for (int ni = 0; ni < 4; ++ni) {
            #pragma unroll
            for (int r = 0; r < 4; ++r) {
                float v = acc[mi][ni][r];
                int row = m0 + wrow * 64 + mi * 16 + lq * 4 + r;
                int col = n0 + wcol * 64 + ni * 16 + c16;
                if (MODE == 1) {
                    Out[(size_t)row * N_out + col] = v;
                } else {
                    int which = col >> 10;
                    int c = col & 1023;
                    int h = c >> 6, d = c & 63;
                    int b = row >> 11, t = row & 2047;
                    int bh = b * H_ + h;
                    if (which == 0)
                        Qb[((size_t)(bh * T_ + t)) * D_ + d] = f2bs(v * 0.1803368801111204f);
                    else if (which == 1)
                        Kb[((size_t)(bh * T_ + t)) * D_ + d] = f2bs(v);
                    else
                        Vt[((size_t)(bh * D_ + d)) * T_ + t] = f2bs(v);
                }
            }
        }
    }
}

// -------- flash attention (r18, equal-best): 4 waves x 32 q-rows, grid 1024 ----
__global__ __launch_bounds__(256, 4)
void attn_fwd(const unsigned short* __restrict__ Qb,
              const unsigned short* __restrict__ Kb,
              const unsigned short* __restrict__ Vt,
              unsigned short* __restrict__ Y) {
    __shared__ alignas(16) unsigned short Ks[2][64 * 64];
    __shared__ alignas(16) unsigned short Vs[2][64 * 64];
    const int tid = threadIdx.x;
    const int wv = tid >> 6;           // 0..3
    const int l = tid & 63;
    const int r32 = l & 31;
    const int hi = l >> 5;
    const int hi8 = hi * 8;
    const int bh = blockIdx.x & 63;    // bid%8 == bh%8 -> same XCD per bh
    const int qc = 15 - (blockIdx.x >> 6);   // longest chunks dispatched first
    const unsigned short* Kp = Kb + (size_t)bh * T_ * D_;
    const unsigned short* Vp = Vt + (size_t)bh * D_ * T_;
    const unsigned short* Qbase = Qb + (size_t)bh * T_ * D_;
    const int b = bh >> 4, h = bh & 15;
    const int srow = tid >> 3;         // 0..31
    const int scs  = tid & 7;
    const int scol_sw = 8 * (scs ^ (srow & 7));
    const int wbase = wv * 512;

    const int q0w = qc * 128 + wv * 32;
    const int nt = 2 * qc + 2;
    const int qg = q0w + r32;

    bf16x8 qf[4];
    #pragma unroll
    for (int ds = 0; ds < 4; ++ds)
        qf[ds] = *(const bf16x8*)&Qbase[(size_t)qg * 64 + ds * 16 + hi8];

    f32x16 o[2];
    #pragma unroll
    for (int e = 0; e < 16; ++e) { o[0][e] = 0.f; o[1][e] = 0.f; }
    float lsum = 0.f;

    gload16(&Kp[(size_t)srow * 64 + scol_sw],        &Ks[0][wbase]);
    gload16(&Kp[(size_t)(srow + 32) * 64 + scol_sw], &Ks[0][2048 + wbase]);
    gload16(&Vp[(size_t)srow * T_ + scol_sw],        &Vs[0][wbase]);
    gload16(&Vp[(size_t)(srow + 32) * T_ + scol_sw], &Vs[0][2048 + wbase]);

    for (int it = 0; it < nt; ++it) {
        const int kb = it * 64;
        __syncthreads();
        if (it + 1 < nt) {
            const int kn = kb + 64;
            unsigned short* Kd = Ks[(it + 1) & 1];
            unsigned short* Vd = Vs[(it + 1) & 1];
            gload16(&Kp[(size_t)(kn + srow) * 64 + scol_sw],        &Kd[wbase]);
            gload16(&Kp[(size_t)(kn + srow + 32) * 64 + scol_sw],   &Kd[2048 + wbase]);
            gload16(&Vp[(size_t)srow * T_ + kn + scol_sw],          &Vd[wbase]);
            gload16(&Vp[(size_t)(srow + 32) * T_ + kn + scol_sw],   &Vd[2048 + wbase]);
        }
        if (kb > q0w + 31) continue;
        const unsigned short* Kl = Ks[it & 1];
        const unsigned short* Vl = Vs[it & 1];

        f32x16 s[2];
        #pragma unroll
        for (int e = 0; e < 16; ++e) { s[0][e] = 0.f; s[1][e] = 0.f; }
        __builtin_amdgcn_s_setprio(1);
        #pragma unroll
        for (int kt = 0; kt < 2; ++kt)
            #pragma unroll
            for (int ds = 0; ds < 4; ++ds) {
                bf16x8 af = *(const bf16x8*)&Kl[swz(32 * kt + r32, ds * 16 + hi8)];
                s[kt] = __builtin_amdgcn_mfma_f32_32x32x16_bf16(af, qf[ds], s[kt], 0, 0, 0);
            }
        __builtin_amdgcn_s_setprio(0);
        if (kb + 63 > q0w) {
            #pragma unroll
            for (int kt = 0; kt < 2; ++kt)
                #pragma unroll
                for (int m = 0; m < 4; ++m)
                    #pragma unroll
                    for (int r = 0; r < 4; ++r)
                        if (kb + 32 * kt + 8 * m + r + 4 * hi > qg)
                            s[kt][4 * m + r] = -1e30f;
        }
        float rs0 = 0.f, rs1 = 0.f, rs2 = 0.f, rs3 = 0.f;
        #pragma unroll
        for (int kt = 0; kt < 2; ++kt)
            #pragma unroll
            for (int m = 0; m < 4; ++m) {
                float p0 = fexp2(s[kt][4 * m + 0]);
                float p1 = fexp2(s[kt][4 * m + 1]);
                float p2 = fexp2(s[kt][4 * m + 2]);
                float p3 = fexp2(s[kt][4 * m + 3]);
                s[kt][4 * m + 0] = p0; s[kt][4 * m + 1] = p1;
                s[kt][4 * m + 2] = p2; s[kt][4 * m + 3] = p3;
                rs0 += p0; rs1 += p1; rs2 += p2; rs3 += p3;
            }
        lsum += (rs0 + rs1) + (rs2 + rs3);
        bf16x8 pb[4];
        #pragma unroll
        for (int ks = 0; ks < 4; ++ks) {
            const int kt = ks >> 1;
            const int m0 = (ks & 1) * 2;
            unsigned a0 = cvtpk(s[kt][4 * m0 + 0], s[kt][4 * m0 + 1]);
            unsigned a1 = cvtpk(s[kt][4 * m0 + 2], s[kt][4 * m0 + 3]);
            unsigned b0 = cvtpk(s[kt][4 * m0 + 4], s[kt][4 * m0 + 5]);
            unsigned b1 = cvtpk(s[kt][4 * m0 + 6], s[kt][4 * m0 + 7]);
            plane32swap(a0, b0, hi);
            plane32swap(a1, b1, hi);
            uint4 u = {a0, a1, b0, b1};
            pb[ks] = *reinterpret_cast<bf16x8*>(&u);
        }
        __builtin_amdgcn_s_setprio(1);
        #pragma unroll
        for (int dt = 0; dt < 2; ++dt)
            #pragma unroll
            for (int ks = 0; ks < 4; ++ks) {
                bf16x8 va = *(const bf16x8*)&Vl[swz(32 * dt + r32, ks * 16 + hi8)];
                o[dt] = __builtin_amdgcn_mfma_f32_32x32x16_bf16(va, pb[ks], o[dt], 0, 0, 0);
            }
        __builtin_amdgcn_s_setprio(0);
    }

    float lt = lsum + __shfl_xor(lsum, 32);
    float inv = 1.f / lt;
    #pragma unroll
    for (int dt = 0; dt < 2; ++dt)
        #pragma unroll
        for (int m = 0; m < 4; ++m) {
            uint2 w;
            w.x = cvtpk(o[dt][4 * m + 0] * inv, o[dt][4 * m + 1] * inv);
            w.y = cvtpk(o[dt][4 * m + 2] * inv, o[dt][4 * m + 3] * inv);
            int d = 32 * dt + 8 * m + 4 * hi;
            *(uint2*)&Y[((size_t)(b * T_ + qg)) * C_ + h * D_ + d] = w;
        }
}

extern "C" void kernel_launch(void* const* d_in, const int* in_sizes, int n_in,
                              void* d_out, int out_size, void* d_ws, size_t ws_size,
                              hipStream_t stream) {
    const float* x     = (const float*)d_in[0];   // [4,2048,1024]
    const float* w_qkv = (const float*)d_in[1];   // [1024,3072]
    const float* w_out = (const float*)d_in[2];   // [1024,1024]
    float* out = (float*)d_out;                   // [4,2048,1024] fp32
    char* ws = (char*)d_ws;

    unsigned short* xb  = (unsigned short*)(ws);                        // 16 MB [8192][1024]
    unsigned short* wqt = (unsigned short*)(ws + (16u << 20));          //  6 MB [3072][1024]
    unsigned short* wot = (unsigned short*)(ws + (22u << 20));          //  2 MB [1024][1024]
    unsigned short* Qb  = (unsigned short*)(ws + (24u << 20));          // 16 MB [64][2048][64]
    unsigned short* Kb  = (unsigned short*)(ws + (40u << 20));          // 16 MB [64][2048][64]
    unsigned short* Vt  = (unsigned short*)(ws + (56u << 20));          // 16 MB [64][64][2048]
    unsigned short* Yb  = (unsigned short*)(ws + (72u << 20));          // 16 MB [8192][1024]

    // 1. fused preprocessing: x->bf16 + both weight transposes (one launch)
    prep_fused<<<9216, 256, 0, stream>>>(x, xb, w_qkv, wqt, w_out, wot);
    // 2. QKV GEMM + scatter -- triple-buffered counted-vmcnt (T4-minimal)
    gemm_bt3<0, 1024><<<dim3(64, 24), 256, 0, stream>>>(xb, wqt, nullptr, 3072, Qb, Kb, Vt);
    // 3. causal flash attention -> Y bf16 (grid 1024 single-chunk)
    attn_fwd<<<1024, 256, 0, stream>>>(Qb, Kb, Vt, Yb);
    // 4. output projection -> fp32 out (proven 2-phase)
    gemm_bt<1><<<dim3(64, 8), 256, 0, stream>>>(Yb, wot, out, 1024, nullptr, nullptr, nullptr, 1024);
}

// Round 20
// 155.794 us; speedup vs baseline: 1.2163x; 1.2163x over previous
//
#include <hip/hip_runtime.h>
#include <hip/hip_bf16.h>

#define B_ 4
#define T_ 2048
#define C_ 1024
#define H_ 16
#define D_ 64

typedef __bf16 bf16x8 __attribute__((ext_vector_type(8)));
typedef float f32x4 __attribute__((ext_vector_type(4)));
typedef float f32x16 __attribute__((ext_vector_type(16)));

__device__ __forceinline__ unsigned short f2bs(float f) {
    __hip_bfloat16 h = __float2bfloat16(f);
    return *reinterpret_cast<unsigned short*>(&h);
}

// raw v_exp_f32 (2^x): one trans op vs OCML exp2f's guarded sequence.
__device__ __forceinline__ float fexp2(float x) {
    float r;
    asm("v_exp_f32 %0, %1" : "=v"(r) : "v"(x));
    return r;
}

// pack two f32 -> one u32 of 2 bf16 (low = a, high = b)
__device__ __forceinline__ unsigned cvtpk(float a, float b) {
    unsigned r;
    asm("v_cvt_pk_bf16_f32 %0, %1, %2" : "=v"(r) : "v"(a), "v"(b));
    return r;
}

// exchange a.hi-lanes <-> b.lo-lanes (T12)
__device__ __forceinline__ void plane32swap(unsigned& a, unsigned& b, int hi) {
#if __has_builtin(__builtin_amdgcn_permlane32_swap)
    typedef int i32x2 __attribute__((ext_vector_type(2)));
    i32x2 r = __builtin_amdgcn_permlane32_swap((int)a, (int)b, false, false);
    a = (unsigned)r.x; b = (unsigned)r.y;
#else
    unsigned v = hi ? a : b;
    unsigned e = __shfl_xor(v, 32);
    unsigned na = hi ? e : a;
    unsigned nb = hi ? b : e;
    a = na; b = nb;
#endif
}

// XOR swizzle for [rows][64] bf16 LDS tiles: permutes 8-elem (16B) chunks
// within a row by row&7 -> spreads column-slice reads across 8 bank-groups.
__device__ __forceinline__ int swz(int row, int col) {
    return (row * 64 + col) ^ ((row & 7) << 3);
}

// async global->LDS 16B: linear LDS dest (wave-uniform base + lane*16).
__device__ __forceinline__ void gload16(const void* g, void* l) {
    auto gp = (const __attribute__((address_space(1))) void*)(g);
    auto lp = (__attribute__((address_space(3))) void*)(uintptr_t)(l);
    __builtin_amdgcn_global_load_lds(gp, lp, 16, 0, 0);
}

// ---- fused preprocessing: x->bf16 convert + both weight transposes ----
__global__ __launch_bounds__(256)
void prep_fused(const float* __restrict__ x, unsigned short* __restrict__ xb,
                const float* __restrict__ in1, unsigned short* __restrict__ out1,
                const float* __restrict__ in2, unsigned short* __restrict__ out2) {
    __shared__ float tile[64][65];
    const int bid = blockIdx.x;
    if (bid < 8192) {
        int i = bid * 256 + threadIdx.x;
        float4 v = ((const float4*)x)[i];
        union { unsigned short h[4]; uint2 u; } pk;
        pk.h[0] = f2bs(v.x); pk.h[1] = f2bs(v.y);
        pk.h[2] = f2bs(v.z); pk.h[3] = f2bs(v.w);
        ((uint2*)xb)[i] = pk.u;
        return;
    }
    const int tb = bid - 8192;
    const int bx = tb & 63;
    const int by = tb >> 6;
    const int tx = threadIdx.x & 63;
    const int ty = threadIdx.x >> 6;
    const bool second = bx >= 48;
    const float* in = second ? in2 : in1;
    unsigned short* out = second ? out2 : out1;
    const int C = second ? 1024 : 3072;
    const int R = 1024;
    const int c0 = (second ? (bx - 48) : bx) * 64;
    const int r0 = by * 64;
    #pragma unroll
    for (int i = 0; i < 16; ++i) {
        int r = ty * 16 + i;
        tile[r][tx] = in[(size_t)(r0 + r) * C + c0 + tx];
    }
    __syncthreads();
    #pragma unroll
    for (int i = 0; i < 16; ++i) {
        int r = ty * 16 + i;
        out[(size_t)(c0 + r) * R + r0 + tx] = f2bs(tile[tx][r]);
    }
}

// ---------------- bf16 MFMA GEMM: C = A[M][K] * Bt[N][K]^T ----------------
// 128^2 tile, BK=64, double-buffered LDS, ONE barrier per K-step, prefetch
// after the barrier. Measured structural ceiling ~660 TF. Five escape
// attempts (8-phase x4, triple-buffer counted-vmcnt) all regressed or
// raced -- the implicit 2-block wave-level overlap IS this structure's
// pipelining, and deeper pipelines that cost residency lose net.
// MODE 0: epilogue scatters into Q (scaled 0.125*log2e), K, V^T (qkv GEMM)
// MODE 1: epilogue writes fp32 to Out[M][N_out] (final projection)
template<int MODE>
__global__ __launch_bounds__(256)
void gemm_bt(const unsigned short* __restrict__ A,
             const unsigned short* __restrict__ Bt,
             float* __restrict__ Out, int N_out,
             unsigned short* __restrict__ Qb,
             unsigned short* __restrict__ Kb,
             unsigned short* __restrict__ Vt,
             int K) {
    __shared__ alignas(16) unsigned short As[2][128 * 64];
    __shared__ alignas(16) unsigned short Bs[2][128 * 64];
    const int tid = threadIdx.x;
    const int l = tid & 63;
    const int c16 = l & 15, lq = l >> 4;
    const int wv = tid >> 6;
    const int wrow = wv >> 1, wcol = wv & 1;
    const int m0 = blockIdx.x * 128, n0 = blockIdx.y * 128;

    f32x4 acc[4][4];
    #pragma unroll
    for (int i = 0; i < 4; ++i)
        #pragma unroll
        for (int j = 0; j < 4; ++j)
            acc[i][j] = f32x4{0.f, 0.f, 0.f, 0.f};

    const int srow = tid >> 3;            // 0..31
    const int scs  = tid & 7;             // 16B chunk within row
    const int ldsbase = (tid & ~63) * 8;  // wave-uniform element base (p=0)

    auto stage = [&](int k0, int buf) {
        #pragma unroll
        for (int p = 0; p < 4; ++p) {
            int row = p * 32 + srow;
            int csw = 8 * (scs ^ (row & 7));   // inverse-swizzled source chunk
            gload16(&A[(size_t)(m0 + row) * K + k0 + csw], &As[buf][p * 2048 + ldsbase]);
            gload16(&Bt[(size_t)(n0 + row) * K + k0 + csw], &Bs[buf][p * 2048 + ldsbase]);
        }
    };

    stage(0, 0);
    const int NK = K >> 6;
    for (int i = 0; i < NK; ++i) {
        __syncthreads();   // drains vmcnt: buf[i&1] staged; buf[i&1]^1 readers done
        if (i + 1 < NK) stage((i + 1) << 6, (i + 1) & 1);
        const unsigned short* Al = As[i & 1];
        const unsigned short* Bl = Bs[i & 1];
        #pragma unroll
        for (int kk = 0; kk < 64; kk += 32) {
            bf16x8 af[4], bfv[4];
            int koff = kk + lq * 8;
            #pragma unroll
            for (int t = 0; t < 4; ++t) {
                af[t]  = *(const bf16x8*)&Al[swz(wrow * 64 + t * 16 + c16, koff)];
                bfv[t] = *(const bf16x8*)&Bl[swz(wcol * 64 + t * 16 + c16, koff)];
            }
            #pragma unroll
            for (int mi = 0; mi < 4; ++mi)
                #pragma unroll
                for (int ni = 0; ni < 4; ++ni)
                    acc[mi][ni] = __builtin_amdgcn_mfma_f32_16x16x32_bf16(
                        af[mi], bfv[ni], acc[mi][ni], 0, 0, 0);
        }
    }

    #pragma unroll
    for (int mi = 0; mi < 4; ++mi) {
        #pragma unroll
        for (int ni = 0; ni < 4; ++ni) {
            #pragma unroll
            for (int r = 0; r < 4; ++r) {
                float v = acc[mi][ni][r];
                int row = m0 + wrow * 64 + mi * 16 + lq * 4 + r;
                int col = n0 + wcol * 64 + ni * 16 + c16;
                if (MODE == 1) {
                    Out[(size_t)row * N_out + col] = v;
                } else {
                    int which = col >> 10;
                    int c = col & 1023;
                    int h = c >> 6, d = c & 63;
                    int b = row >> 11, t = row & 2047;
                    int bh = b * H_ + h;
                    if (which == 0)  // fold 1/sqrt(64) * log2(e) so attn uses exp2
                        Qb[((size_t)(bh * T_ + t)) * D_ + d] = f2bs(v * 0.1803368801111204f);
                    else if (which == 1)
                        Kb[((size_t)(bh * T_ + t)) * D_ + d] = f2bs(v);
                    else
                        Vt[((size_t)(bh * D_ + d)) * T_ + t] = f2bs(v);
                }
            }
        }
    }
}

// -------- flash attention: 4 waves x 32 q-rows, KVBLK=64, 32x32x16 MFMA --------
// T12 in-register P (cvt_pk + permlane32_swap), fixed-max softmax via native
// v_exp_f32, 4-way partial sums, K/V dbuf gload_lds, one barrier/tile.
// Grid 1024 single-chunk (16 qc x 64 bh), longest-first, 4 blocks/CU.
__global__ __launch_bounds__(256, 4)
void attn_fwd(const unsigned short* __restrict__ Qb,
              const unsigned short* __restrict__ Kb,
              const unsigned short* __restrict__ Vt,
              unsigned short* __restrict__ Y) {
    __shared__ alignas(16) unsigned short Ks[2][64 * 64];
    __shared__ alignas(16) unsigned short Vs[2][64 * 64];
    const int tid = threadIdx.x;
    const int wv = tid >> 6;           // 0..3
    const int l = tid & 63;
    const int r32 = l & 31;
    const int hi = l >> 5;
    const int hi8 = hi * 8;
    const int bh = blockIdx.x & 63;    // bid%8 == bh%8 -> same XCD per bh
    const int qc = 15 - (blockIdx.x >> 6);   // longest chunks dispatched first
    const unsigned short* Kp = Kb + (size_t)bh * T_ * D_;
    const unsigned short* Vp = Vt + (size_t)bh * D_ * T_;
    const unsigned short* Qbase = Qb + (size_t)bh * T_ * D_;
    const int b = bh >> 4, h = bh & 15;
    const int srow = tid >> 3;         // 0..31
    const int scs  = tid & 7;
    const int scol_sw = 8 * (scs ^ (srow & 7));
    const int wbase = wv * 512;

    const int q0w = qc * 128 + wv * 32;
    const int nt = 2 * qc + 2;
    const int qg = q0w + r32;

    bf16x8 qf[4];
    #pragma unroll
    for (int ds = 0; ds < 4; ++ds)
        qf[ds] = *(const bf16x8*)&Qbase[(size_t)qg * 64 + ds * 16 + hi8];

    f32x16 o[2];
    #pragma unroll
    for (int e = 0; e < 16; ++e) { o[0][e] = 0.f; o[1][e] = 0.f; }
    float lsum = 0.f;

    gload16(&Kp[(size_t)srow * 64 + scol_sw],        &Ks[0][wbase]);
    gload16(&Kp[(size_t)(srow + 32) * 64 + scol_sw], &Ks[0][2048 + wbase]);
    gload16(&Vp[(size_t)srow * T_ + scol_sw],        &Vs[0][wbase]);
    gload16(&Vp[(size_t)(srow + 32) * T_ + scol_sw], &Vs[0][2048 + wbase]);

    for (int it = 0; it < nt; ++it) {
        const int kb = it * 64;
        __syncthreads();   // drains vmcnt: buf[it&1] staged; buf[it^1] readers done
        if (it + 1 < nt) {
            const int kn = kb + 64;
            unsigned short* Kd = Ks[(it + 1) & 1];
            unsigned short* Vd = Vs[(it + 1) & 1];
            gload16(&Kp[(size_t)(kn + srow) * 64 + scol_sw],        &Kd[wbase]);
            gload16(&Kp[(size_t)(kn + srow + 32) * 64 + scol_sw],   &Kd[2048 + wbase]);
            gload16(&Vp[(size_t)srow * T_ + kn + scol_sw],          &Vd[wbase]);
            gload16(&Vp[(size_t)(srow + 32) * T_ + kn + scol_sw],   &Vd[2048 + wbase]);
        }
        if (kb > q0w + 31) continue;   // wave-uniform: fully-masked tile
        const unsigned short* Kl = Ks[it & 1];
        const unsigned short* Vl = Vs[it & 1];

        f32x16 s[2];
        #pragma unroll
        for (int e = 0; e < 16; ++e) { s[0][e] = 0.f; s[1][e] = 0.f; }
        __builtin_amdgcn_s_setprio(1);
        #pragma unroll
        for (int kt = 0; kt < 2; ++kt)
            #pragma unroll
            for (int ds = 0; ds < 4; ++ds) {
                bf16x8 af = *(const bf16x8*)&Kl[swz(32 * kt + r32, ds * 16 + hi8)];
                s[kt] = __builtin_amdgcn_mfma_f32_32x32x16_bf16(af, qf[ds], s[kt], 0, 0, 0);
            }
        __builtin_amdgcn_s_setprio(0);
        if (kb + 63 > q0w) {
            #pragma unroll
            for (int kt = 0; kt < 2; ++kt)
                #pragma unroll
                for (int m = 0; m < 4; ++m)
                    #pragma unroll
                    for (int r = 0; r < 4; ++r)
                        if (kb + 32 * kt + 8 * m + r + 4 * hi > qg)
                            s[kt][4 * m + r] = -1e30f;
        }
        float rs0 = 0.f, rs1 = 0.f, rs2 = 0.f, rs3 = 0.f;
        #pragma unroll
        for (int kt = 0; kt < 2; ++kt)
            #pragma unroll
            for (int m = 0; m < 4; ++m) {
                float p0 = fexp2(s[kt][4 * m + 0]);
                float p1 = fexp2(s[kt][4 * m + 1]);
                float p2 = fexp2(s[kt][4 * m + 2]);
                float p3 = fexp2(s[kt][4 * m + 3]);
                s[kt][4 * m + 0] = p0; s[kt][4 * m + 1] = p1;
                s[kt][4 * m + 2] = p2; s[kt][4 * m + 3] = p3;
                rs0 += p0; rs1 += p1; rs2 += p2; rs3 += p3;
            }
        lsum += (rs0 + rs1) + (rs2 + rs3);
        bf16x8 pb[4];
        #pragma unroll
        for (int ks = 0; ks < 4; ++ks) {
            const int kt = ks >> 1;
            const int m0 = (ks & 1) * 2;
            unsigned a0 = cvtpk(s[kt][4 * m0 + 0], s[kt][4 * m0 + 1]);
            unsigned a1 = cvtpk(s[kt][4 * m0 + 2], s[kt][4 * m0 + 3]);
            unsigned b0 = cvtpk(s[kt][4 * m0 + 4], s[kt][4 * m0 + 5]);
            unsigned b1 = cvtpk(s[kt][4 * m0 + 6], s[kt][4 * m0 + 7]);
            plane32swap(a0, b0, hi);
            plane32swap(a1, b1, hi);
            uint4 u = {a0, a1, b0, b1};
            pb[ks] = *reinterpret_cast<bf16x8*>(&u);
        }
        __builtin_amdgcn_s_setprio(1);
        #pragma unroll
        for (int dt = 0; dt < 2; ++dt)
            #pragma unroll
            for (int ks = 0; ks < 4; ++ks) {
                bf16x8 va = *(const bf16x8*)&Vl[swz(32 * dt + r32, ks * 16 + hi8)];
                o[dt] = __builtin_amdgcn_mfma_f32_32x32x16_bf16(va, pb[ks], o[dt], 0, 0, 0);
            }
        __builtin_amdgcn_s_setprio(0);
    }

    float lt = lsum + __shfl_xor(lsum, 32);
    float inv = 1.f / lt;
    #pragma unroll
    for (int dt = 0; dt < 2; ++dt)
        #pragma unroll
        for (int m = 0; m < 4; ++m) {
            uint2 w;
            w.x = cvtpk(o[dt][4 * m + 0] * inv, o[dt][4 * m + 1] * inv);
            w.y = cvtpk(o[dt][4 * m + 2] * inv, o[dt][4 * m + 3] * inv);
            int d = 32 * dt + 8 * m + 4 * hi;
            *(uint2*)&Y[((size_t)(b * T_ + qg)) * C_ + h * D_ + d] = w;
        }
}

extern "C" void kernel_launch(void* const* d_in, const int* in_sizes, int n_in,
                              void* d_out, int out_size, void* d_ws, size_t ws_size,
                              hipStream_t stream) {
    const float* x     = (const float*)d_in[0];   // [4,2048,1024]
    const float* w_qkv = (const float*)d_in[1];   // [1024,3072]
    const float* w_out = (const float*)d_in[2];   // [1024,1024]
    float* out = (float*)d_out;                   // [4,2048,1024] fp32
    char* ws = (char*)d_ws;

    unsigned short* xb  = (unsigned short*)(ws);                        // 16 MB [8192][1024]
    unsigned short* wqt = (unsigned short*)(ws + (16u << 20));          //  6 MB [3072][1024]
    unsigned short* wot = (unsigned short*)(ws + (22u << 20));          //  2 MB [1024][1024]
    unsigned short* Qb  = (unsigned short*)(ws + (24u << 20));          // 16 MB [64][2048][64]
    unsigned short* Kb  = (unsigned short*)(ws + (40u << 20));          // 16 MB [64][2048][64]
    unsigned short* Vt  = (unsigned short*)(ws + (56u << 20));          // 16 MB [64][64][2048]
    unsigned short* Yb  = (unsigned short*)(ws + (72u << 20));          // 16 MB [8192][1024]

    // 1. fused preprocessing: x->bf16 + both weight transposes (one launch)
    prep_fused<<<9216, 256, 0, stream>>>(x, xb, w_qkv, wqt, w_out, wot);
    // 2. QKV GEMM + scatter (BK=64, the proven 2-phase kernel)
    gemm_bt<0><<<dim3(64, 24), 256, 0, stream>>>(xb, wqt, nullptr, 3072, Qb, Kb, Vt, 1024);
    // 3. causal flash attention -> Y bf16 (grid 1024 single-chunk, 4 blocks/CU)
    attn_fwd<<<1024, 256, 0, stream>>>(Qb, Kb, Vt, Yb);
    // 4. output projection -> fp32 out
    gemm_bt<1><<<dim3(64, 8), 256, 0, stream>>>(Yb, wot, out, 1024, nullptr, nullptr, nullptr, 1024);
}